// Round 28
// baseline (189.254 us; speedup 1.0000x reference)
//
#include <hip/hip_runtime.h>
#include <hip/hip_bf16.h>

// Problem constants
constexpr int Bn = 4, Sn = 2048, Dn = 1024, Hn = 16, DKn = 64;
constexpr int Mrows = Bn * Sn;  // 8192

typedef __attribute__((ext_vector_type(8))) short short8;
typedef __attribute__((ext_vector_type(4))) float f32x4;
typedef __attribute__((ext_vector_type(4))) unsigned int u32x4;

#define DEV __device__ __forceinline__

constexpr float QSCL = 0.18033688f;  // 0.125 * log2(e), folded into Q proj

// fp32 -> bf16 RNE, scalar (epilogue scatter only)
DEV unsigned short f2bf(float f) {
    unsigned u = __builtin_bit_cast(unsigned, f);
    u += 0x7FFFu + ((u >> 16) & 1u);
    return (unsigned short)(u >> 16);
}
// fp32 pair -> packed bf16x2 via v_cvt_pk_bf16_f32 (hardware RNE)
DEV unsigned pk2(float a, float b) {
    __hip_bfloat162 h = __float22bfloat162_rn(float2{a, b});
    unsigned u;
    __builtin_memcpy(&u, &h, 4);
    return u;
}
// 2^x via v_exp_f32
DEV float exp2a(float x) {
    float r;
    asm("v_exp_f32 %0, %1" : "=v"(r) : "v"(x));
    return r;
}

// ---------------------------------------------------------------------------
// Weights fp32 -> bf16, one matrix per blockIdx.y. 8 elems/thread.
// ---------------------------------------------------------------------------
__global__ __launch_bounds__(256) void cvt_w(const float* __restrict__ W0,
                                             const float* __restrict__ W1,
                                             const float* __restrict__ W2,
                                             const float* __restrict__ W3,
                                             unsigned short* __restrict__ Out) {
    const float* src = blockIdx.y == 0 ? W0
                     : blockIdx.y == 1 ? W1
                     : blockIdx.y == 2 ? W2 : W3;
    size_t off = ((size_t)blockIdx.x * 256 + threadIdx.x) * 8;
    const float4* s = (const float4*)(src + off);
    float4 a = s[0], b = s[1];
    u32x4 p = {pk2(a.x, a.y), pk2(a.z, a.w), pk2(b.x, b.y), pk2(b.z, b.w)};
    *(u32x4*)(Out + (size_t)blockIdx.y * (Dn * Dn) + off) = p;
}

// ---------------------------------------------------------------------------
// GEMM body: C[m,n] = sum_k A[m,k] * W[n,k]  (y = x @ W^T), M=8192, N=K=1024.
// R17 PROVEN inner structure. 128x128 tile, BK=64, 512 threads (8 waves,
// 2x4 grid, 32x64/wave). LDS rows padded to 72 shorts (144B).
// m0/n0 passed in (XCD-aware remap by caller).
// oscale: multiplied into outputs (Q proj gets 0.125*log2e for attn).
// ---------------------------------------------------------------------------
template <bool ABF16, bool BBF16, bool OUTF32>
DEV void gemm_body(const void* __restrict__ Ap, const void* __restrict__ Bw,
                   void* __restrict__ Out, float oscale, int m0, int n0) {
    __shared__ alignas(16) unsigned short As[128 * 72];
    __shared__ alignas(16) unsigned short Bs[128 * 72];

    const int tid = threadIdx.x;  // 0..511
    const int lane = tid & 63;
    const int w = tid >> 6;                 // 0..7
    const int wm = (w >> 1) * 32;           // 4 m-waves x 32 rows
    const int wn = (w & 1) * 64;            // 2 n-waves x 64 cols
    const int g = lane >> 4, q15 = lane & 15;

    f32x4 acc[2][4] = {};

    const int srow = tid >> 2, sseg = tid & 3;  // 128 rows x 4 segs of 16 elems

    const float* Af = (const float*)Ap;
    const unsigned short* Ab = (const unsigned short*)Ap;
    const float* Bf = (const float*)Bw;
    const unsigned short* Bb = (const unsigned short*)Bw;

    float4 fa[4], fb[4];
    u32x4 ua[2], ub[2];

    auto loadA = [&](int kk) {
        if constexpr (ABF16) {
            const u32x4* s =
                (const u32x4*)(Ab + (size_t)(m0 + srow) * Dn + kk + sseg * 16);
            ua[0] = s[0];
            ua[1] = s[1];
        } else {
            const float4* s =
                (const float4*)(Af + (size_t)(m0 + srow) * Dn + kk + sseg * 16);
            fa[0] = s[0]; fa[1] = s[1]; fa[2] = s[2]; fa[3] = s[3];
        }
    };
    auto loadB = [&](int kk) {
        if constexpr (BBF16) {
            const u32x4* s =
                (const u32x4*)(Bb + (size_t)(n0 + srow) * Dn + kk + sseg * 16);
            ub[0] = s[0];
            ub[1] = s[1];
        } else {
            const float4* s =
                (const float4*)(Bf + (size_t)(n0 + srow) * Dn + kk + sseg * 16);
            fb[0] = s[0]; fb[1] = s[1]; fb[2] = s[2]; fb[3] = s[3];
        }
    };
    auto store = [&]() {
        u32x4* da = (u32x4*)(&As[srow * 72 + sseg * 16]);
        if constexpr (ABF16) {
            da[0] = ua[0];
            da[1] = ua[1];
        } else {
            u32x4 p0 = {pk2(fa[0].x, fa[0].y), pk2(fa[0].z, fa[0].w),
                        pk2(fa[1].x, fa[1].y), pk2(fa[1].z, fa[1].w)};
            u32x4 p1 = {pk2(fa[2].x, fa[2].y), pk2(fa[2].z, fa[2].w),
                        pk2(fa[3].x, fa[3].y), pk2(fa[3].z, fa[3].w)};
            da[0] = p0;
            da[1] = p1;
        }
        u32x4* db = (u32x4*)(&Bs[srow * 72 + sseg * 16]);
        if constexpr (BBF16) {
            db[0] = ub[0];
            db[1] = ub[1];
        } else {
            u32x4 q0 = {pk2(fb[0].x, fb[0].y), pk2(fb[0].z, fb[0].w),
                        pk2(fb[1].x, fb[1].y), pk2(fb[1].z, fb[1].w)};
            u32x4 q1 = {pk2(fb[2].x, fb[2].y), pk2(fb[2].z, fb[2].w),
                        pk2(fb[3].x, fb[3].y), pk2(fb[3].z, fb[3].w)};
            db[0] = q0;
            db[1] = q1;
        }
    };

    loadA(0);
    loadB(0);
    for (int kk = 0; kk < Dn; kk += 64) {
        store();
        __syncthreads();
        if (kk + 64 < Dn) {
            loadA(kk + 64);
            loadB(kk + 64);
        }

#pragma unroll
        for (int ks = 0; ks < 2; ++ks) {
            short8 af[2], bf4[4];
#pragma unroll
            for (int mf = 0; mf < 2; ++mf)
                af[mf] = __builtin_bit_cast(
                    short8, *(const u32x4*)(&As[(wm + mf * 16 + q15) * 72 +
                                                ks * 32 + g * 8]));
#pragma unroll
            for (int nf = 0; nf < 4; ++nf)
                bf4[nf] = __builtin_bit_cast(
                    short8, *(const u32x4*)(&Bs[(wn + nf * 16 + q15) * 72 +
                                                ks * 32 + g * 8]));
#pragma unroll
            for (int mf = 0; mf < 2; ++mf)
#pragma unroll
                for (int nf = 0; nf < 4; ++nf)
                    acc[mf][nf] = __builtin_amdgcn_mfma_f32_16x16x32_bf16(
                        af[mf], bf4[nf], acc[mf][nf], 0, 0, 0);
        }
        __syncthreads();
    }

#pragma unroll
    for (int mf = 0; mf < 2; ++mf)
#pragma unroll
        for (int nf = 0; nf < 4; ++nf)
#pragma unroll
            for (int r = 0; r < 4; ++r) {
                int m = m0 + wm + mf * 16 + 4 * g + r;
                int n = n0 + wn + nf * 16 + q15;
                float val = acc[mf][nf][r] * oscale;
                if (OUTF32) {
                    ((float*)Out)[(size_t)m * Dn + n] = val;
                } else {
                    int b = m >> 11, s = m & (Sn - 1);
                    int h = n >> 6, dk = n & 63;
                    ((unsigned short*)Out)[(((size_t)(b * Hn + h) * Sn + s) << 6) +
                                           dk] = f2bf(val);
                }
            }
}

// Standalone GEMM (fallback Wo). XCD remap: all 8 n-blocks of one A-panel
// share bid%8 -> same XCD L2 (R12 win).
template <bool ABF16, bool BBF16, bool OUTF32>
__global__ __launch_bounds__(512) void gemm_nt(const void* __restrict__ Ap,
                                               const void* __restrict__ Bw,
                                               void* __restrict__ Out,
                                               float oscale) {
    const int bid = (int)(blockIdx.y * gridDim.x + blockIdx.x);
    const int xcd = bid & 7;
    const int jj = bid >> 3;
    const int m0 = (xcd + ((jj & 7) << 3)) * 128;
    const int n0 = (jj >> 3) * 128;
    gemm_body<ABF16, BBF16, OUTF32>(Ap, Bw, Out, oscale, m0, n0);
}

// ---------------------------------------------------------------------------
// R28: M-SPLIT Wo GEMM — 64x128 tile, bf16 A + bf16 B, fp32 out.
// Mechanism: BM 128->64 doubles the grid (512->1024 = 4 blocks/CU = 32
// waves/CU, 2x latency hiding) while CONSERVING HBM traffic: each A row is
// still read by exactly N/BN = 8 n-blocks, and the extra W re-reads hit
// the L2-resident 2MB weight (R26's N-split failed because it doubled
// A-traffic; M-split doesn't). 8 waves in 2m x 4n grid, 32x32/wave,
// acc[2][2]. A staging: 64 rows x 8 segs of 16B (1 load/thread).
// LDS 27.6KB -> 4 blocks/CU fit. Per-XCD A set: 16 panels x 128KB = 2MB.
// ---------------------------------------------------------------------------
__global__ __launch_bounds__(512) void gemm_nt64(
    const unsigned short* __restrict__ Ab, const unsigned short* __restrict__ Bb,
    float* __restrict__ Out, float oscale) {
    __shared__ alignas(16) unsigned short As[64 * 72];
    __shared__ alignas(16) unsigned short Bs[128 * 72];

    const int tid = threadIdx.x;  // 0..511
    const int bid = (int)blockIdx.x;
    const int xcd = bid & 7;
    const int jj = bid >> 3;                        // 0..127
    const int m0 = (xcd + ((jj & 15) << 3)) * 64;   // 128 m-panels of 64
    const int n0 = (jj >> 4) * 128;                 // 8 n-panels of 128
    const int lane = tid & 63;
    const int w = tid >> 6;        // 0..7
    const int wm = (w >> 2) * 32;  // 2 m-waves x 32 rows
    const int wn = (w & 3) * 32;   // 4 n-waves x 32 cols
    const int g = lane >> 4, q15 = lane & 15;

    f32x4 acc[2][2] = {};

    const int arow = tid >> 3, aseg = tid & 7;  // A: 64 rows x 8 segs of 8
    const int brow = tid >> 2, bseg = tid & 3;  // B: 128 rows x 4 segs of 16

    u32x4 ua0, ub[2];

    auto loadA = [&](int kk) {
        ua0 = *(const u32x4*)(Ab + (size_t)(m0 + arow) * Dn + kk + aseg * 8);
    };
    auto loadB = [&](int kk) {
        const u32x4* s =
            (const u32x4*)(Bb + (size_t)(n0 + brow) * Dn + kk + bseg * 16);
        ub[0] = s[0];
        ub[1] = s[1];
    };
    auto store = [&]() {
        *(u32x4*)(&As[arow * 72 + aseg * 8]) = ua0;
        u32x4* db = (u32x4*)(&Bs[brow * 72 + bseg * 16]);
        db[0] = ub[0];
        db[1] = ub[1];
    };

    loadA(0);
    loadB(0);
    for (int kk = 0; kk < Dn; kk += 64) {
        store();
        __syncthreads();
        if (kk + 64 < Dn) {
            loadA(kk + 64);
            loadB(kk + 64);
        }

#pragma unroll
        for (int ks = 0; ks < 2; ++ks) {
            short8 af[2], bf4[2];
#pragma unroll
            for (int mf = 0; mf < 2; ++mf)
                af[mf] = __builtin_bit_cast(
                    short8, *(const u32x4*)(&As[(wm + mf * 16 + q15) * 72 +
                                                ks * 32 + g * 8]));
#pragma unroll
            for (int nf = 0; nf < 2; ++nf)
                bf4[nf] = __builtin_bit_cast(
                    short8, *(const u32x4*)(&Bs[(wn + nf * 16 + q15) * 72 +
                                                ks * 32 + g * 8]));
#pragma unroll
            for (int mf = 0; mf < 2; ++mf)
#pragma unroll
                for (int nf = 0; nf < 2; ++nf)
                    acc[mf][nf] = __builtin_amdgcn_mfma_f32_16x16x32_bf16(
                        af[mf], bf4[nf], acc[mf][nf], 0, 0, 0);
        }
        __syncthreads();
    }

#pragma unroll
    for (int mf = 0; mf < 2; ++mf)
#pragma unroll
        for (int nf = 0; nf < 2; ++nf)
#pragma unroll
            for (int r = 0; r < 4; ++r) {
                int m = m0 + wm + mf * 16 + 4 * g + r;
                int n = n0 + wn + nf * 16 + q15;
                Out[(size_t)m * Dn + n] = acc[mf][nf][r] * oscale;
            }
}

// ---------------------------------------------------------------------------
// FUSED QKV projection (R23 win): one dispatch, 1536 blocks. Decode keeps
// the R12 XCD locality per z: xcd=bid&7, jj=bid>>3, z=jj>>6 (blocks 0..511
// are z=0, etc.), inner=jj&63: m0=(xcd+8*(inner&7))*128, n0=(inner>>3)*128.
// ---------------------------------------------------------------------------
__global__ __launch_bounds__(512) void gemm_qkv(
    const float* __restrict__ q, const float* __restrict__ k,
    const float* __restrict__ v, const unsigned short* __restrict__ Wb,
    unsigned short* __restrict__ Qb, unsigned short* __restrict__ Kb,
    unsigned short* __restrict__ Vb) {
    const int bid = (int)blockIdx.x;
    const int xcd = bid & 7;
    const int jj = bid >> 3;
    const int z = jj >> 6;
    const int inner = jj & 63;
    const int m0 = (xcd + ((inner & 7) << 3)) * 128;
    const int n0 = (inner >> 3) * 128;
    const float* A = z == 0 ? q : z == 1 ? k : v;
    const unsigned short* W = Wb + (size_t)z * Dn * Dn;
    unsigned short* Out = z == 0 ? Qb : z == 1 ? Kb : Vb;
    const float osc = z == 0 ? QSCL : 1.0f;
    gemm_body<false, true, false>(A, W, Out, osc, m0, n0);
}

// ---------------------------------------------------------------------------
// Causal flash attention — PROVEN R23 version (frozen; R10/R13/R24
// restructures all regressed). 8-WAVE blocks (R16) + XCD-aware remap (R20:
// FETCH 147->30MB). 1-D grid of 512: xcd=bid&7, pair=(bid>>3)&7, t=bid>>6,
// bh=8t+xcd -> all 8 pair-blocks of a head share one XCD.
// Each staged 64-kv tile feeds 128 q-rows (8 waves x 16). Pairing {15-p,p}
// of 128-row chunks -> uniform 34 iters/block. Per-wave diagonal jdiag =
// 2c + (w>>2); past-diagonal tiles skipped via wave-uniform guard.
// Q arrives PRE-SCALED by 0.125*log2e (scores already log2-domain).
// Single-buffer LDS:
//   Kt: [64kv][64dk] XOR-swizzled (byte ^= (row&7)<<4)
//   Vt: [64dk][64 kv-PERMUTED] (R11 win): col_new(kv) = (kv&32)|((kv&12)
//   <<1)|((kv&16)>>2)|(kv&3) makes the PV B-frag the lane's own pkk regs.
// QK^T swapped; T13 defer-max; T14 reg-prefetch; denominator via ones-A
// MFMA. NOTE: no min-waves in launch_bounds (R7: cap -> 456MB spill).
// ---------------------------------------------------------------------------
__global__ __launch_bounds__(512) void attn_fwd(
    const unsigned short* __restrict__ Qb, const unsigned short* __restrict__ Kb,
    const unsigned short* __restrict__ Vb, unsigned short* __restrict__ Xb) {
    __shared__ alignas(16) unsigned short Kt[64 * 64];
    __shared__ alignas(16) unsigned short Vt[64 * 64];

    const int tid = threadIdx.x;  // 0..511
    const int bid = (int)blockIdx.x;  // 0..511
    const int pair = (bid >> 3) & 7;  // 0..7
    const int bh = ((bid >> 6) << 3) + (bid & 7);  // 8*t + xcd
    const int b = bh >> 4, h = bh & 15;
    const int lane = tid & 63, w = tid >> 6;  // w: 0..7
    const int g = lane >> 4, q15 = lane & 15;

    const unsigned short* Qh = Qb + (size_t)bh * Sn * DKn;
    const unsigned short* Kh = Kb + (size_t)bh * Sn * DKn;
    const unsigned short* Vh = Vb + (size_t)bh * Sn * DKn;

    const int st_row = tid >> 3, st_seg = tid & 7;  // K staging: 1x16B/thread
    const int sv_kv = tid & 63, sv_g = tid >> 6;    // V staging: 8 dk/thread
    const int sel = sv_kv & 1;
    // permuted byte col base in Vt (bit0 of kv preserved by col_new)
    const int kv_even = sv_kv & ~1;
    const unsigned kvp = (unsigned)(((kv_even & 32) | ((kv_even & 12) << 1) |
                                     ((kv_even & 16) >> 2) | (kv_even & 3)) *
                                    2);

    // constant all-ones bf16 A-fragment for the denominator MFMA
    const short8 ones = {0x3F80, 0x3F80, 0x3F80, 0x3F80,
                         0x3F80, 0x3F80, 0x3F80, 0x3F80};

    u32x4 kr0, vr0;  // prefetch registers
    auto load_kv = [&](int j) {
        kr0 = *(const u32x4*)(Kh + (size_t)(j * 64 + st_row) * DKn + st_seg * 8);
        vr0 = *(const u32x4*)(Vh + (size_t)(j * 64 + sv_kv) * DKn + sv_g * 8);
    };

    for (int hp = 0; hp < 2; ++hp) {
        const int c = hp == 0 ? (15 - pair) : pair;  // 128-row chunk index
        const int jmax = 2 * c + 1;
        const int jdiag = 2 * c + (w >> 2);  // this wave's diagonal tile
        const int qg = c * 128 + w * 16 + q15;  // this lane's q row

        short8 qf[2];
#pragma unroll
        for (int ks = 0; ks < 2; ++ks)
            qf[ks] = __builtin_bit_cast(
                short8, *(const u32x4*)(Qh + (size_t)qg * DKn + ks * 32 + g * 8));

        f32x4 xacc[4] = {};  // O^T: xacc[mf][r] = O[q=q15][d=mf*16+4g+r]
        f32x4 xl = {};       // denominator accumulator (all r identical)
        float m_run = -1e30f;  // running max (log2 domain, Q pre-scaled)

        load_kv(0);
        for (int j = 0; j <= jmax; ++j) {
            // ---- write staged KV regs to LDS ----
            {
                unsigned b0 = ((unsigned)(st_row * 128 + st_seg * 16)) ^
                              ((unsigned)(st_row & 7) << 4);
                *(u32x4*)((char*)Kt + b0) = kr0;
            }
            {
                int dk0 = sv_g * 8;
#pragma unroll
                for (int i = 0; i < 4; ++i) {
                    unsigned mine = vr0[i];
                    unsigned theirs = (unsigned)__shfl_xor((int)mine, 1);
                    int dk_abs = dk0 + 2 * i + sel;
                    unsigned out = sel ? ((theirs >> 16) | (mine & 0xffff0000u))
                                       : ((mine & 0xffffu) | (theirs << 16));
                    unsigned byteoff = ((unsigned)(dk_abs * 128) + kvp) ^
                                       ((unsigned)(dk_abs & 7) << 4);
                    *(unsigned*)((char*)Vt + byteoff) = out;
                }
            }
            __syncthreads();

            // next tile's loads in flight under the compute
            if (j < jmax) load_kv(j + 1);

            if (j <= jdiag) {  // wave-uniform guard (past-diag tiles skipped)
                // ---- QK^T (swapped): sacc rows = kv, cols = q ----
                f32x4 sacc[4] = {};
#pragma unroll
                for (int mf = 0; mf < 4; ++mf) {
                    int row = mf * 16 + q15;
#pragma unroll
                    for (int ks = 0; ks < 2; ++ks) {
                        unsigned byteoff =
                            ((unsigned)(row * 128 + ks * 64 + g * 16)) ^
                            ((unsigned)(row & 7) << 4);
                        short8 kf = __builtin_bit_cast(
                            short8, *(const u32x4*)((char*)Kt + byteoff));
                        sacc[mf] = __builtin_amdgcn_mfma_f32_16x16x32_bf16(
                            kf, qf[ks], sacc[mf], 0, 0, 0);
                    }
                }

                // ---- mask + online softmax (scores already log2-domain) ----
                float p[4][4];
                float pmax = -1e30f;
                const bool diag = (j == jdiag);
#pragma unroll
                for (int mf = 0; mf < 4; ++mf)
#pragma unroll
                    for (int r = 0; r < 4; ++r) {
                        float sv = sacc[mf][r];
                        if (diag) {
                            int kvg = j * 64 + mf * 16 + 4 * g + r;
                            if (kvg > qg) sv = -1e30f;
                        }
                        p[mf][r] = sv;
                        pmax = fmaxf(pmax, sv);
                    }
                pmax = fmaxf(pmax, __shfl_xor(pmax, 16));
                pmax = fmaxf(pmax, __shfl_xor(pmax, 32));
                if (__any(pmax > m_run + 8.f)) {  // T13 defer-max
                    float mnew = fmaxf(m_run, pmax);
                    float corr = exp2a(m_run - mnew);
#pragma unroll
                    for (int mf = 0; mf < 4; ++mf)
#pragma unroll
                        for (int r = 0; r < 4; ++r) xacc[mf][r] *= corr;
#pragma unroll
                    for (int r = 0; r < 4; ++r) xl[r] *= corr;
                    m_run = mnew;
                }
#pragma unroll
                for (int mf = 0; mf < 4; ++mf)
#pragma unroll
                    for (int r = 0; r < 4; ++r)
                        p[mf][r] = exp2a(p[mf][r] - m_run);

                // ---- pack P; PV B-frag lane-local (V cols pre-permuted) ----
                unsigned pkk[4][2];
#pragma unroll
                for (int mf = 0; mf < 4; ++mf) {
                    pkk[mf][0] = pk2(p[mf][0], p[mf][1]);
                    pkk[mf][1] = pk2(p[mf][2], p[mf][3]);
                }
#pragma unroll
                for (int ks = 0; ks < 2; ++ks) {
                    u32x4 tmp = {pkk[2 * ks][0], pkk[2 * ks][1],
                                 pkk[2 * ks + 1][0], pkk[2 * ks + 1][1]};
                    short8 pb = __builtin_bit_cast(short8, tmp);
                    // denominator: l += sum_kv P^T[kv][q] via ones-A MFMA
                    xl = __builtin_amdgcn_mfma_f32_16x16x32_bf16(ones, pb, xl,
                                                                 0, 0, 0);
#pragma unroll
                    for (int mf = 0; mf < 4; ++mf) {
                        int row = mf * 16 + q15;
                        unsigned byteoff =
                            ((unsigned)(row * 128 + ks * 64 + g * 16)) ^
                            ((unsigned)(row & 7) << 4);
                        short8 vf = __builtin_bit_cast(
                            short8, *(const u32x4*)((char*)Vt + byteoff));
                        xacc[mf] = __builtin_amdgcn_mfma_f32_16x16x32_bf16(
                            vf, pb, xacc[mf], 0, 0, 0);
                    }
                }
            }
            __syncthreads();
        }

        // ---- epilogue: lane owns q=q15 row; 4x 8B stores ----
        float inv = 1.0f / xl[0];
        size_t rowbase = (size_t)(b * Sn + c * 128 + w * 16 + q15) * Dn + h * 64;
#pragma unroll
        for (int mf = 0; mf < 4; ++mf) {
            unsigned w0 = pk2(xacc[mf][0] * inv, xacc[mf][1] * inv);
            unsigned w1 = pk2(xacc[mf][2] * inv, xacc[mf][3] * inv);
            uint2 val = {w0, w1};
            *(uint2*)(Xb + rowbase + mf * 16 + 4 * g) = val;
        }
    }
}

// ---------------------------------------------------------------------------
// Launch. ws layout (bf16): Qb | Kb | Vb | Xb (16 MiB each) | Wb (8 MiB,
// 4 weight matrices bf16, if ws_size permits).
// ---------------------------------------------------------------------------
extern "C" void kernel_launch(void* const* d_in, const int* in_sizes, int n_in,
                              void* d_out, int out_size, void* d_ws, size_t ws_size,
                              hipStream_t stream) {
    (void)in_sizes; (void)n_in; (void)out_size;
    const float* q = (const float*)d_in[0];
    const float* k = (const float*)d_in[1];
    const float* v = (const float*)d_in[2];
    // d_in[3] = mask (causal tril; implemented analytically)
    const float* Wq = (const float*)d_in[4];
    const float* Wk = (const float*)d_in[5];
    const float* Wv = (const float*)d_in[6];
    const float* Wo = (const float*)d_in[7];

    unsigned short* Qb = (unsigned short*)d_ws;
    unsigned short* Kb = Qb + (size_t)Mrows * Dn;
    unsigned short* Vb = Kb + (size_t)Mrows * Dn;
    unsigned short* Xb = Vb + (size_t)Mrows * Dn;
    unsigned short* Wb = Xb + (size_t)Mrows * Dn;

    const size_t needW =
        (size_t)4 * Mrows * Dn * 2 + (size_t)4 * Dn * Dn * 2;  // 64 + 8 MiB
    const bool useWb = ws_size >= needW;

    dim3 blk(256);
    dim3 gblk(512);
    dim3 ggrid(Dn / 128, Mrows / 128);  // (8, 64) = 512 blocks (fallback)
    dim3 agrid(512);  // 1-D, XCD-aware decode inside the kernel

    if (useWb) {
        cvt_w<<<dim3(Dn * Dn / (256 * 8), 4), blk, 0, stream>>>(Wq, Wk, Wv, Wo, Wb);
        const unsigned short* Wob = Wb + (size_t)3 * Dn * Dn;
        gemm_qkv<<<dim3(1536), gblk, 0, stream>>>(q, k, v, Wb, Qb, Kb, Vb);
        attn_fwd<<<agrid, gblk, 0, stream>>>(Qb, Kb, Vb, Xb);
        gemm_nt64<<<dim3(1024), gblk, 0, stream>>>(Xb, Wob, (float*)d_out, 1.0f);
    } else {
        gemm_nt<false, false, false><<<ggrid, gblk, 0, stream>>>(q, Wq, Qb, QSCL);
        gemm_nt<false, false, false><<<ggrid, gblk, 0, stream>>>(k, Wk, Kb, 1.0f);
        gemm_nt<false, false, false><<<ggrid, gblk, 0, stream>>>(v, Wv, Vb, 1.0f);
        attn_fwd<<<agrid, gblk, 0, stream>>>(Qb, Kb, Vb, Xb);
        gemm_nt<true, false, true><<<ggrid, gblk, 0, stream>>>(Xb, Wo, d_out, 1.0f);
    }
}

// Round 29
// 183.347 us; speedup vs baseline: 1.0322x; 1.0322x over previous
//
#include <hip/hip_runtime.h>
#include <hip/hip_bf16.h>

// Problem constants
constexpr int Bn = 4, Sn = 2048, Dn = 1024, Hn = 16, DKn = 64;
constexpr int Mrows = Bn * Sn;  // 8192

typedef __attribute__((ext_vector_type(8))) short short8;
typedef __attribute__((ext_vector_type(4))) float f32x4;
typedef __attribute__((ext_vector_type(4))) unsigned int u32x4;

#define DEV __device__ __forceinline__

constexpr float QSCL = 0.18033688f;  // 0.125 * log2(e), folded into Q proj

// fp32 -> bf16 RNE, scalar (epilogue scatter only)
DEV unsigned short f2bf(float f) {
    unsigned u = __builtin_bit_cast(unsigned, f);
    u += 0x7FFFu + ((u >> 16) & 1u);
    return (unsigned short)(u >> 16);
}
// fp32 pair -> packed bf16x2 via v_cvt_pk_bf16_f32 (hardware RNE)
DEV unsigned pk2(float a, float b) {
    __hip_bfloat162 h = __float22bfloat162_rn(float2{a, b});
    unsigned u;
    __builtin_memcpy(&u, &h, 4);
    return u;
}
// 2^x via v_exp_f32
DEV float exp2a(float x) {
    float r;
    asm("v_exp_f32 %0, %1" : "=v"(r) : "v"(x));
    return r;
}

// ---------------------------------------------------------------------------
// Weights fp32 -> bf16, one matrix per blockIdx.y. 8 elems/thread.
// ---------------------------------------------------------------------------
__global__ __launch_bounds__(256) void cvt_w(const float* __restrict__ W0,
                                             const float* __restrict__ W1,
                                             const float* __restrict__ W2,
                                             const float* __restrict__ W3,
                                             unsigned short* __restrict__ Out) {
    const float* src = blockIdx.y == 0 ? W0
                     : blockIdx.y == 1 ? W1
                     : blockIdx.y == 2 ? W2 : W3;
    size_t off = ((size_t)blockIdx.x * 256 + threadIdx.x) * 8;
    const float4* s = (const float4*)(src + off);
    float4 a = s[0], b = s[1];
    u32x4 p = {pk2(a.x, a.y), pk2(a.z, a.w), pk2(b.x, b.y), pk2(b.z, b.w)};
    *(u32x4*)(Out + (size_t)blockIdx.y * (Dn * Dn) + off) = p;
}

// ---------------------------------------------------------------------------
// GEMM body: C[m,n] = sum_k A[m,k] * W[n,k]  (y = x @ W^T), M=8192, N=K=1024.
// R17 PROVEN inner structure. 128x128 tile is the balanced point of this
// 2-barrier structure (R24/R26/R28: every compute-per-barrier dilution —
// KVBLK=128, 128x64, 64x128 — lost more than residency gained). BK=64,
// 512 threads (8 waves, 2x4 grid, 32x64/wave). LDS rows padded to 72
// shorts (144B). m0/n0 passed in (XCD-aware remap by caller).
// oscale: multiplied into outputs (Q proj gets 0.125*log2e for attn).
// ---------------------------------------------------------------------------
template <bool ABF16, bool BBF16, bool OUTF32>
DEV void gemm_body(const void* __restrict__ Ap, const void* __restrict__ Bw,
                   void* __restrict__ Out, float oscale, int m0, int n0) {
    __shared__ alignas(16) unsigned short As[128 * 72];
    __shared__ alignas(16) unsigned short Bs[128 * 72];

    const int tid = threadIdx.x;  // 0..511
    const int lane = tid & 63;
    const int w = tid >> 6;                 // 0..7
    const int wm = (w >> 1) * 32;           // 4 m-waves x 32 rows
    const int wn = (w & 1) * 64;            // 2 n-waves x 64 cols
    const int g = lane >> 4, q15 = lane & 15;

    f32x4 acc[2][4] = {};

    const int srow = tid >> 2, sseg = tid & 3;  // 128 rows x 4 segs of 16 elems

    const float* Af = (const float*)Ap;
    const unsigned short* Ab = (const unsigned short*)Ap;
    const float* Bf = (const float*)Bw;
    const unsigned short* Bb = (const unsigned short*)Bw;

    float4 fa[4], fb[4];
    u32x4 ua[2], ub[2];

    auto loadA = [&](int kk) {
        if constexpr (ABF16) {
            const u32x4* s =
                (const u32x4*)(Ab + (size_t)(m0 + srow) * Dn + kk + sseg * 16);
            ua[0] = s[0];
            ua[1] = s[1];
        } else {
            const float4* s =
                (const float4*)(Af + (size_t)(m0 + srow) * Dn + kk + sseg * 16);
            fa[0] = s[0]; fa[1] = s[1]; fa[2] = s[2]; fa[3] = s[3];
        }
    };
    auto loadB = [&](int kk) {
        if constexpr (BBF16) {
            const u32x4* s =
                (const u32x4*)(Bb + (size_t)(n0 + srow) * Dn + kk + sseg * 16);
            ub[0] = s[0];
            ub[1] = s[1];
        } else {
            const float4* s =
                (const float4*)(Bf + (size_t)(n0 + srow) * Dn + kk + sseg * 16);
            fb[0] = s[0]; fb[1] = s[1]; fb[2] = s[2]; fb[3] = s[3];
        }
    };
    auto store = [&]() {
        u32x4* da = (u32x4*)(&As[srow * 72 + sseg * 16]);
        if constexpr (ABF16) {
            da[0] = ua[0];
            da[1] = ua[1];
        } else {
            u32x4 p0 = {pk2(fa[0].x, fa[0].y), pk2(fa[0].z, fa[0].w),
                        pk2(fa[1].x, fa[1].y), pk2(fa[1].z, fa[1].w)};
            u32x4 p1 = {pk2(fa[2].x, fa[2].y), pk2(fa[2].z, fa[2].w),
                        pk2(fa[3].x, fa[3].y), pk2(fa[3].z, fa[3].w)};
            da[0] = p0;
            da[1] = p1;
        }
        u32x4* db = (u32x4*)(&Bs[srow * 72 + sseg * 16]);
        if constexpr (BBF16) {
            db[0] = ub[0];
            db[1] = ub[1];
        } else {
            u32x4 q0 = {pk2(fb[0].x, fb[0].y), pk2(fb[0].z, fb[0].w),
                        pk2(fb[1].x, fb[1].y), pk2(fb[1].z, fb[1].w)};
            u32x4 q1 = {pk2(fb[2].x, fb[2].y), pk2(fb[2].z, fb[2].w),
                        pk2(fb[3].x, fb[3].y), pk2(fb[3].z, fb[3].w)};
            db[0] = q0;
            db[1] = q1;
        }
    };

    loadA(0);
    loadB(0);
    for (int kk = 0; kk < Dn; kk += 64) {
        store();
        __syncthreads();
        if (kk + 64 < Dn) {
            loadA(kk + 64);
            loadB(kk + 64);
        }

#pragma unroll
        for (int ks = 0; ks < 2; ++ks) {
            short8 af[2], bf4[4];
#pragma unroll
            for (int mf = 0; mf < 2; ++mf)
                af[mf] = __builtin_bit_cast(
                    short8, *(const u32x4*)(&As[(wm + mf * 16 + q15) * 72 +
                                                ks * 32 + g * 8]));
#pragma unroll
            for (int nf = 0; nf < 4; ++nf)
                bf4[nf] = __builtin_bit_cast(
                    short8, *(const u32x4*)(&Bs[(wn + nf * 16 + q15) * 72 +
                                                ks * 32 + g * 8]));
#pragma unroll
            for (int mf = 0; mf < 2; ++mf)
#pragma unroll
                for (int nf = 0; nf < 4; ++nf)
                    acc[mf][nf] = __builtin_amdgcn_mfma_f32_16x16x32_bf16(
                        af[mf], bf4[nf], acc[mf][nf], 0, 0, 0);
        }
        __syncthreads();
    }

#pragma unroll
    for (int mf = 0; mf < 2; ++mf)
#pragma unroll
        for (int nf = 0; nf < 4; ++nf)
#pragma unroll
            for (int r = 0; r < 4; ++r) {
                int m = m0 + wm + mf * 16 + 4 * g + r;
                int n = n0 + wn + nf * 16 + q15;
                float val = acc[mf][nf][r] * oscale;
                if (OUTF32) {
                    ((float*)Out)[(size_t)m * Dn + n] = val;
                } else {
                    int b = m >> 11, s = m & (Sn - 1);
                    int h = n >> 6, dk = n & 63;
                    ((unsigned short*)Out)[(((size_t)(b * Hn + h) * Sn + s) << 6) +
                                           dk] = f2bf(val);
                }
            }
}

// Standalone GEMM (Wo projection). XCD remap: all 8 n-blocks of one A-panel
// share bid%8 -> same XCD L2 (R12 win).
template <bool ABF16, bool BBF16, bool OUTF32>
__global__ __launch_bounds__(512) void gemm_nt(const void* __restrict__ Ap,
                                               const void* __restrict__ Bw,
                                               void* __restrict__ Out,
                                               float oscale) {
    const int bid = (int)(blockIdx.y * gridDim.x + blockIdx.x);
    const int xcd = bid & 7;
    const int jj = bid >> 3;
    const int m0 = (xcd + ((jj & 7) << 3)) * 128;
    const int n0 = (jj >> 3) * 128;
    gemm_body<ABF16, BBF16, OUTF32>(Ap, Bw, Out, oscale, m0, n0);
}

// ---------------------------------------------------------------------------
// FUSED QKV projection (R23 win): one dispatch, 1536 blocks. Decode keeps
// the R12 XCD locality per z: xcd=bid&7, jj=bid>>3, z=jj>>6 (blocks 0..511
// are z=0, etc.), inner=jj&63: m0=(xcd+8*(inner&7))*128, n0=(inner>>3)*128.
// ---------------------------------------------------------------------------
__global__ __launch_bounds__(512) void gemm_qkv(
    const float* __restrict__ q, const float* __restrict__ k,
    const float* __restrict__ v, const unsigned short* __restrict__ Wb,
    unsigned short* __restrict__ Qb, unsigned short* __restrict__ Kb,
    unsigned short* __restrict__ Vb) {
    const int bid = (int)blockIdx.x;
    const int xcd = bid & 7;
    const int jj = bid >> 3;
    const int z = jj >> 6;
    const int inner = jj & 63;
    const int m0 = (xcd + ((inner & 7) << 3)) * 128;
    const int n0 = (inner >> 3) * 128;
    const float* A = z == 0 ? q : z == 1 ? k : v;
    const unsigned short* W = Wb + (size_t)z * Dn * Dn;
    unsigned short* Out = z == 0 ? Qb : z == 1 ? Kb : Vb;
    const float osc = z == 0 ? QSCL : 1.0f;
    gemm_body<false, true, false>(A, W, Out, osc, m0, n0);
}

// ---------------------------------------------------------------------------
// Causal flash attention — PROVEN R23 version (frozen). 8-WAVE blocks
// (R16) + XCD-aware remap (R20: FETCH 147->30MB). 1-D grid of 512:
// xcd=bid&7, pair=(bid>>3)&7, t=bid>>6, bh=8t+xcd -> all 8 pair-blocks of
// a head share one XCD. Each staged 64-kv tile feeds 128 q-rows (8 waves x
// 16). Pairing {15-p,p} of 128-row chunks -> uniform 34 iters/block.
// Per-wave diagonal jdiag = 2c + (w>>2); past-diagonal tiles skipped via
// wave-uniform guard. Q arrives PRE-SCALED by 0.125*log2e.
// Single-buffer LDS:
//   Kt: [64kv][64dk] XOR-swizzled (byte ^= (row&7)<<4)
//   Vt: [64dk][64 kv-PERMUTED] (R11 win): col_new(kv) = (kv&32)|((kv&12)
//   <<1)|((kv&16)>>2)|(kv&3) makes the PV B-frag the lane's own pkk regs.
// QK^T swapped; T13 defer-max; T14 reg-prefetch; denominator via ones-A
// MFMA. NOTE: no min-waves in launch_bounds (R7: cap -> 456MB spill).
// ---------------------------------------------------------------------------
__global__ __launch_bounds__(512) void attn_fwd(
    const unsigned short* __restrict__ Qb, const unsigned short* __restrict__ Kb,
    const unsigned short* __restrict__ Vb, unsigned short* __restrict__ Xb) {
    __shared__ alignas(16) unsigned short Kt[64 * 64];
    __shared__ alignas(16) unsigned short Vt[64 * 64];

    const int tid = threadIdx.x;  // 0..511
    const int bid = (int)blockIdx.x;  // 0..511
    const int pair = (bid >> 3) & 7;  // 0..7
    const int bh = ((bid >> 6) << 3) + (bid & 7);  // 8*t + xcd
    const int b = bh >> 4, h = bh & 15;
    const int lane = tid & 63, w = tid >> 6;  // w: 0..7
    const int g = lane >> 4, q15 = lane & 15;

    const unsigned short* Qh = Qb + (size_t)bh * Sn * DKn;
    const unsigned short* Kh = Kb + (size_t)bh * Sn * DKn;
    const unsigned short* Vh = Vb + (size_t)bh * Sn * DKn;

    const int st_row = tid >> 3, st_seg = tid & 7;  // K staging: 1x16B/thread
    const int sv_kv = tid & 63, sv_g = tid >> 6;    // V staging: 8 dk/thread
    const int sel = sv_kv & 1;
    // permuted byte col base in Vt (bit0 of kv preserved by col_new)
    const int kv_even = sv_kv & ~1;
    const unsigned kvp = (unsigned)(((kv_even & 32) | ((kv_even & 12) << 1) |
                                     ((kv_even & 16) >> 2) | (kv_even & 3)) *
                                    2);

    // constant all-ones bf16 A-fragment for the denominator MFMA
    const short8 ones = {0x3F80, 0x3F80, 0x3F80, 0x3F80,
                         0x3F80, 0x3F80, 0x3F80, 0x3F80};

    u32x4 kr0, vr0;  // prefetch registers
    auto load_kv = [&](int j) {
        kr0 = *(const u32x4*)(Kh + (size_t)(j * 64 + st_row) * DKn + st_seg * 8);
        vr0 = *(const u32x4*)(Vh + (size_t)(j * 64 + sv_kv) * DKn + sv_g * 8);
    };

    for (int hp = 0; hp < 2; ++hp) {
        const int c = hp == 0 ? (15 - pair) : pair;  // 128-row chunk index
        const int jmax = 2 * c + 1;
        const int jdiag = 2 * c + (w >> 2);  // this wave's diagonal tile
        const int qg = c * 128 + w * 16 + q15;  // this lane's q row

        short8 qf[2];
#pragma unroll
        for (int ks = 0; ks < 2; ++ks)
            qf[ks] = __builtin_bit_cast(
                short8, *(const u32x4*)(Qh + (size_t)qg * DKn + ks * 32 + g * 8));

        f32x4 xacc[4] = {};  // O^T: xacc[mf][r] = O[q=q15][d=mf*16+4g+r]
        f32x4 xl = {};       // denominator accumulator (all r identical)
        float m_run = -1e30f;  // running max (log2 domain, Q pre-scaled)

        load_kv(0);
        for (int j = 0; j <= jmax; ++j) {
            // ---- write staged KV regs to LDS ----
            {
                unsigned b0 = ((unsigned)(st_row * 128 + st_seg * 16)) ^
                              ((unsigned)(st_row & 7) << 4);
                *(u32x4*)((char*)Kt + b0) = kr0;
            }
            {
                int dk0 = sv_g * 8;
#pragma unroll
                for (int i = 0; i < 4; ++i) {
                    unsigned mine = vr0[i];
                    unsigned theirs = (unsigned)__shfl_xor((int)mine, 1);
                    int dk_abs = dk0 + 2 * i + sel;
                    unsigned out = sel ? ((theirs >> 16) | (mine & 0xffff0000u))
                                       : ((mine & 0xffffu) | (theirs << 16));
                    unsigned byteoff = ((unsigned)(dk_abs * 128) + kvp) ^
                                       ((unsigned)(dk_abs & 7) << 4);
                    *(unsigned*)((char*)Vt + byteoff) = out;
                }
            }
            __syncthreads();

            // next tile's loads in flight under the compute
            if (j < jmax) load_kv(j + 1);

            if (j <= jdiag) {  // wave-uniform guard (past-diag tiles skipped)
                // ---- QK^T (swapped): sacc rows = kv, cols = q ----
                f32x4 sacc[4] = {};
#pragma unroll
                for (int mf = 0; mf < 4; ++mf) {
                    int row = mf * 16 + q15;
#pragma unroll
                    for (int ks = 0; ks < 2; ++ks) {
                        unsigned byteoff =
                            ((unsigned)(row * 128 + ks * 64 + g * 16)) ^
                            ((unsigned)(row & 7) << 4);
                        short8 kf = __builtin_bit_cast(
                            short8, *(const u32x4*)((char*)Kt + byteoff));
                        sacc[mf] = __builtin_amdgcn_mfma_f32_16x16x32_bf16(
                            kf, qf[ks], sacc[mf], 0, 0, 0);
                    }
                }

                // ---- mask + online softmax (scores already log2-domain) ----
                float p[4][4];
                float pmax = -1e30f;
                const bool diag = (j == jdiag);
#pragma unroll
                for (int mf = 0; mf < 4; ++mf)
#pragma unroll
                    for (int r = 0; r < 4; ++r) {
                        float sv = sacc[mf][r];
                        if (diag) {
                            int kvg = j * 64 + mf * 16 + 4 * g + r;
                            if (kvg > qg) sv = -1e30f;
                        }
                        p[mf][r] = sv;
                        pmax = fmaxf(pmax, sv);
                    }
                pmax = fmaxf(pmax, __shfl_xor(pmax, 16));
                pmax = fmaxf(pmax, __shfl_xor(pmax, 32));
                if (__any(pmax > m_run + 8.f)) {  // T13 defer-max
                    float mnew = fmaxf(m_run, pmax);
                    float corr = exp2a(m_run - mnew);
#pragma unroll
                    for (int mf = 0; mf < 4; ++mf)
#pragma unroll
                        for (int r = 0; r < 4; ++r) xacc[mf][r] *= corr;
#pragma unroll
                    for (int r = 0; r < 4; ++r) xl[r] *= corr;
                    m_run = mnew;
                }
#pragma unroll
                for (int mf = 0; mf < 4; ++mf)
#pragma unroll
                    for (int r = 0; r < 4; ++r)
                        p[mf][r] = exp2a(p[mf][r] - m_run);

                // ---- pack P; PV B-frag lane-local (V cols pre-permuted) ----
                unsigned pkk[4][2];
#pragma unroll
                for (int mf = 0; mf < 4; ++mf) {
                    pkk[mf][0] = pk2(p[mf][0], p[mf][1]);
                    pkk[mf][1] = pk2(p[mf][2], p[mf][3]);
                }
#pragma unroll
                for (int ks = 0; ks < 2; ++ks) {
                    u32x4 tmp = {pkk[2 * ks][0], pkk[2 * ks][1],
                                 pkk[2 * ks + 1][0], pkk[2 * ks + 1][1]};
                    short8 pb = __builtin_bit_cast(short8, tmp);
                    // denominator: l += sum_kv P^T[kv][q] via ones-A MFMA
                    xl = __builtin_amdgcn_mfma_f32_16x16x32_bf16(ones, pb, xl,
                                                                 0, 0, 0);
#pragma unroll
                    for (int mf = 0; mf < 4; ++mf) {
                        int row = mf * 16 + q15;
                        unsigned byteoff =
                            ((unsigned)(row * 128 + ks * 64 + g * 16)) ^
                            ((unsigned)(row & 7) << 4);
                        short8 vf = __builtin_bit_cast(
                            short8, *(const u32x4*)((char*)Vt + byteoff));
                        xacc[mf] = __builtin_amdgcn_mfma_f32_16x16x32_bf16(
                            vf, pb, xacc[mf], 0, 0, 0);
                    }
                }
            }
            __syncthreads();
        }

        // ---- epilogue: lane owns q=q15 row; 4x 8B stores ----
        float inv = 1.0f / xl[0];
        size_t rowbase = (size_t)(b * Sn + c * 128 + w * 16 + q15) * Dn + h * 64;
#pragma unroll
        for (int mf = 0; mf < 4; ++mf) {
            unsigned w0 = pk2(xacc[mf][0] * inv, xacc[mf][1] * inv);
            unsigned w1 = pk2(xacc[mf][2] * inv, xacc[mf][3] * inv);
            uint2 val = {w0, w1};
            *(uint2*)(Xb + rowbase + mf * 16 + 4 * g) = val;
        }
    }
}

// ---------------------------------------------------------------------------
// Launch. ws layout (bf16): Qb | Kb | Vb | Xb (16 MiB each) | Wb (8 MiB,
// 4 weight matrices bf16, if ws_size permits).
// ---------------------------------------------------------------------------
extern "C" void kernel_launch(void* const* d_in, const int* in_sizes, int n_in,
                              void* d_out, int out_size, void* d_ws, size_t ws_size,
                              hipStream_t stream) {
    (void)in_sizes; (void)n_in; (void)out_size;
    const float* q = (const float*)d_in[0];
    const float* k = (const float*)d_in[1];
    const float* v = (const float*)d_in[2];
    // d_in[3] = mask (causal tril; implemented analytically)
    const float* Wq = (const float*)d_in[4];
    const float* Wk = (const float*)d_in[5];
    const float* Wv = (const float*)d_in[6];
    const float* Wo = (const float*)d_in[7];

    unsigned short* Qb = (unsigned short*)d_ws;
    unsigned short* Kb = Qb + (size_t)Mrows * Dn;
    unsigned short* Vb = Kb + (size_t)Mrows * Dn;
    unsigned short* Xb = Vb + (size_t)Mrows * Dn;
    unsigned short* Wb = Xb + (size_t)Mrows * Dn;

    const size_t needW =
        (size_t)4 * Mrows * Dn * 2 + (size_t)4 * Dn * Dn * 2;  // 64 + 8 MiB
    const bool useWb = ws_size >= needW;

    dim3 blk(256);
    dim3 gblk(512);
    dim3 ggrid(Dn / 128, Mrows / 128);  // (8, 64) = 512 blocks
    dim3 agrid(512);  // 1-D, XCD-aware decode inside the kernel

    if (useWb) {
        cvt_w<<<dim3(Dn * Dn / (256 * 8), 4), blk, 0, stream>>>(Wq, Wk, Wv, Wo, Wb);
        const unsigned short* Wob = Wb + (size_t)3 * Dn * Dn;
        gemm_qkv<<<dim3(1536), gblk, 0, stream>>>(q, k, v, Wb, Qb, Kb, Vb);
        attn_fwd<<<agrid, gblk, 0, stream>>>(Qb, Kb, Vb, Xb);
        gemm_nt<true, true, true><<<ggrid, gblk, 0, stream>>>(Xb, Wob, d_out, 1.0f);
    } else {
        gemm_nt<false, false, false><<<ggrid, gblk, 0, stream>>>(q, Wq, Qb, QSCL);
        gemm_nt<false, false, false><<<ggrid, gblk, 0, stream>>>(k, Wk, Kb, 1.0f);
        gemm_nt<false, false, false><<<ggrid, gblk, 0, stream>>>(v, Wv, Vb, 1.0f);
        attn_fwd<<<agrid, gblk, 0, stream>>>(Qb, Kb, Vb, Xb);
        gemm_nt<true, false, true><<<ggrid, gblk, 0, stream>>>(Xb, Wo, d_out, 1.0f);
    }
}